// Round 13
// baseline (307.206 us; speedup 1.0000x reference)
//
#include <hip/hip_runtime.h>
#include <hip/hip_fp16.h>
#include <hip/hip_cooperative_groups.h>

namespace cg = cooperative_groups;

#define N_NODES 50000
#define N_PAD   50048
#define N_EDGES 800000
#define D_IN    128
#define D_HID   64

#define NB         196                // buckets of 256 nodes
#define EB_CHUNK   4096               // edges per binning chunk
#define ESTRIDE    4864               // per-bucket temp capacity (mean 4096 + 12 sigma)
#define CSTRIDE    (ESTRIDE + 256)    // per-bucket csr capacity (+256 self-loops)

typedef __bf16 bf16x8 __attribute__((ext_vector_type(8)));
typedef float  f32x4  __attribute__((ext_vector_type(4)));

struct MegaParams {
  const int* e_src; const int* e_dst;
  unsigned* bfill; unsigned* temp;
  const float* W1; const float* W2; const float* W3;
  __bf16 *Wh1, *Wl1, *Wh2, *Wl2, *Wh3, *Wl3;
  unsigned* rowptr; unsigned* rowend; float* dis; unsigned short* csr;
  const float* x; __half* xwA; __half* xwB;
  const float4 *b1, *b2, *b3;
  float4* out;
};

// ---------------- W -> MFMA-B-fragment-order bf16 hi/lo ----------------

template <int K>
__device__ __forceinline__ void pack_w(const float* __restrict__ W,
                                       __bf16* __restrict__ Bh, __bf16* __restrict__ Bl, int i) {
  constexpr int KS = K / 32;
  int j = i & 7, lane = (i >> 3) & 63, rest = i >> 9;
  int ct = rest / KS, ks = rest - ct * KS;
  int k = ks * 32 + ((lane >> 4) << 3) + j;
  int c = ct * 16 + (lane & 15);
  float v = W[k * 64 + c];
  __bf16 hb = (__bf16)v;
  Bh[i] = hb;
  Bl[i] = (__bf16)(v - (float)hb);
}

// ---------------- layer-1 gemm (256-thread sub-block, split-bf16 3 products) ----------------

__device__ __forceinline__ void gemm1_sub(int bid, int tid,
                                          const float* __restrict__ Xf,
                                          const __bf16* __restrict__ Bh,
                                          const __bf16* __restrict__ Bl,
                                          __half* __restrict__ Y) {
  constexpr int K = D_IN, KS = K / 32;
  const int wave = tid >> 6;
  const int lane = tid & 63;
  const int row0 = bid * 64 + wave * 16;
  const int row_a = min(row0 + (lane & 15), N_NODES - 1);
  const int q8 = (lane >> 4) << 3;

  f32x4 acc[4];
#pragma unroll
  for (int ct = 0; ct < 4; ct++) acc[ct] = (f32x4){0.f, 0.f, 0.f, 0.f};

#pragma unroll
  for (int ks = 0; ks < KS; ks++) {
    bf16x8 ah, al;
    const float4* xr4 = reinterpret_cast<const float4*>(Xf + (size_t)row_a * K);
    float4 f0 = xr4[ks * 8 + (q8 >> 2) + 0];
    float4 f1 = xr4[ks * 8 + (q8 >> 2) + 1];
#pragma unroll
    for (int j = 0; j < 4; j++) {
      float a0 = (&f0.x)[j], a1 = (&f1.x)[j];
      __bf16 h0 = (__bf16)a0, h1 = (__bf16)a1;
      ah[j] = h0;     al[j] = (__bf16)(a0 - (float)h0);
      ah[4 + j] = h1; al[4 + j] = (__bf16)(a1 - (float)h1);
    }
#pragma unroll
    for (int ct = 0; ct < 4; ct++) {
      bf16x8 bh = *reinterpret_cast<const bf16x8*>(Bh + (size_t)((ct * KS + ks) * 64 + lane) * 8);
      bf16x8 bl = *reinterpret_cast<const bf16x8*>(Bl + (size_t)((ct * KS + ks) * 64 + lane) * 8);
      acc[ct] = __builtin_amdgcn_mfma_f32_16x16x32_bf16(ah, bh, acc[ct], 0, 0, 0);
      acc[ct] = __builtin_amdgcn_mfma_f32_16x16x32_bf16(ah, bl, acc[ct], 0, 0, 0);
      acc[ct] = __builtin_amdgcn_mfma_f32_16x16x32_bf16(al, bh, acc[ct], 0, 0, 0);
    }
  }

  // C/D: col = lane&15, row = (lane>>4)*4 + reg   [m89-verified]
  const int rbase = row0 + ((lane >> 4) << 2);
  const int c     = lane & 15;
#pragma unroll
  for (int ct = 0; ct < 4; ct++)
#pragma unroll
    for (int r = 0; r < 4; r++) {
      int row = rbase + r;
      if (row < N_NODES)
        Y[(size_t)row * 64 + ct * 16 + c] = __float2half_rn(acc[ct][r]);
    }
}

// ---------------- agg core (R9-proven), result in acc[8] on grp==0 lanes ----------------

__device__ __forceinline__ void agg_core(int node, int lane, int sub, int grp,
                                         const float4* __restrict__ XW4,
                                         const unsigned* __restrict__ rowptr,
                                         const unsigned* __restrict__ rowend,
                                         const unsigned short* __restrict__ csr,
                                         const float* __restrict__ dis,
                                         float* __restrict__ accout) {
  const float disd = dis[node];
  unsigned beg = rowptr[node], end = rowend[node];
  float acc0[8] = {0,0,0,0,0,0,0,0};
  float acc1[8] = {0,0,0,0,0,0,0,0};

  for (unsigned j = beg; j < end; j += 64) {
    int nj = (int)min(64u, end - j);
    unsigned s = 0u; float nrm = 0.f;
    if (lane < nj) {
      s = csr[j + lane];                    // 2B coalesced
      nrm = dis[s] * disd;
    }
    for (int k = 0; k < nj; k += 16) {
      int e0 = k + grp;
      unsigned s0 = (unsigned)__shfl((int)s, e0);
      float    n0 = __shfl(nrm, e0);
      float4 v0 = XW4[(size_t)s0 * 8 + sub];           // 16B = 8 fp16
      const __half2* h0 = reinterpret_cast<const __half2*>(&v0);
#pragma unroll
      for (int q = 0; q < 4; q++) {
        float2 f = __half22float2(h0[q]);
        acc0[2*q]   += n0 * f.x;
        acc0[2*q+1] += n0 * f.y;
      }
      if (k + 8 < nj) {                                 // wave-uniform guard
        int e1 = k + grp + 8;
        unsigned s1 = (unsigned)__shfl((int)s, e1);
        float    n1 = __shfl(nrm, e1);
        float4 v1 = XW4[(size_t)s1 * 8 + sub];
        const __half2* h1 = reinterpret_cast<const __half2*>(&v1);
#pragma unroll
        for (int q = 0; q < 4; q++) {
          float2 f = __half22float2(h1[q]);
          acc1[2*q]   += n1 * f.x;
          acc1[2*q+1] += n1 * f.y;
        }
      }
    }
  }

#pragma unroll
  for (int i = 0; i < 8; i++) {
    float a = acc0[i] + acc1[i];
    a += __shfl_xor(a, 8);
    a += __shfl_xor(a, 16);
    a += __shfl_xor(a, 32);
    accout[i] = a;
  }
}

// ---------------- fused agg(+bias,relu) -> LDS -> gemm for one 16-node tile ----------------

__device__ __forceinline__ void agg_gemm_tile(int v, int t, float (*hld)[68],
                                              const float4* __restrict__ XW4,
                                              const unsigned* __restrict__ rowptr,
                                              const unsigned* __restrict__ rowend,
                                              const unsigned short* __restrict__ csr,
                                              const float* __restrict__ dis,
                                              const float4* __restrict__ bias4,
                                              const __bf16* __restrict__ Bh,
                                              const __bf16* __restrict__ Bl,
                                              __half* __restrict__ Y) {
  const int wave = t >> 6;
  const int lane = t & 63;
  const int sub  = lane & 7;
  const int grp  = lane >> 3;
  const int node = v * 16 + wave;

  float acc[8];
  agg_core(node, lane, sub, grp, XW4, rowptr, rowend, csr, dis, acc);

  if (grp == 0) {
    float4 ba = bias4[sub * 2], bb = bias4[sub * 2 + 1];
    acc[0] += ba.x; acc[1] += ba.y; acc[2] += ba.z; acc[3] += ba.w;
    acc[4] += bb.x; acc[5] += bb.y; acc[6] += bb.z; acc[7] += bb.w;
    float4 o0, o1;
    o0.x = fmaxf(acc[0], 0.f); o0.y = fmaxf(acc[1], 0.f);
    o0.z = fmaxf(acc[2], 0.f); o0.w = fmaxf(acc[3], 0.f);
    o1.x = fmaxf(acc[4], 0.f); o1.y = fmaxf(acc[5], 0.f);
    o1.z = fmaxf(acc[6], 0.f); o1.w = fmaxf(acc[7], 0.f);
    *reinterpret_cast<float4*>(&hld[wave][sub * 8])     = o0;
    *reinterpret_cast<float4*>(&hld[wave][sub * 8 + 4]) = o1;
  }
  __syncthreads();

  if (wave < 4) {                       // gemm phase: wave = col-tile ct
    const int ct = wave;
    const int r16 = lane & 15;
    const int q8  = (lane >> 4) << 3;
    f32x4 gacc = (f32x4){0.f, 0.f, 0.f, 0.f};
#pragma unroll
    for (int ks = 0; ks < 2; ks++) {
      float4 f0 = *reinterpret_cast<const float4*>(&hld[r16][ks * 32 + q8]);
      float4 f1 = *reinterpret_cast<const float4*>(&hld[r16][ks * 32 + q8 + 4]);
      bf16x8 ah, al;
#pragma unroll
      for (int j = 0; j < 4; j++) {
        float a0 = (&f0.x)[j], a1 = (&f1.x)[j];
        __bf16 h0 = (__bf16)a0, h1 = (__bf16)a1;
        ah[j] = h0;     al[j] = (__bf16)(a0 - (float)h0);
        ah[4 + j] = h1; al[4 + j] = (__bf16)(a1 - (float)h1);
      }
      bf16x8 bh = *reinterpret_cast<const bf16x8*>(Bh + (size_t)((ct * 2 + ks) * 64 + lane) * 8);
      bf16x8 bl = *reinterpret_cast<const bf16x8*>(Bl + (size_t)((ct * 2 + ks) * 64 + lane) * 8);
      gacc = __builtin_amdgcn_mfma_f32_16x16x32_bf16(ah, bh, gacc, 0, 0, 0);
      gacc = __builtin_amdgcn_mfma_f32_16x16x32_bf16(ah, bl, gacc, 0, 0, 0);
      gacc = __builtin_amdgcn_mfma_f32_16x16x32_bf16(al, bh, gacc, 0, 0, 0);
    }
    const int rbase = v * 16 + ((lane >> 4) << 2);
    const int c     = lane & 15;
#pragma unroll
    for (int r = 0; r < 4; r++)
      Y[(size_t)(rbase + r) * 64 + ct * 16 + c] = __float2half_rn(gacc[r]);
  }
  __syncthreads();                      // hld reused next stride iteration
}

// ---------------- the cooperative mega-kernel ----------------

__global__ __launch_bounds__(1024) void k_mega(MegaParams p) {
  cg::grid_group grid = cg::this_grid();
  __shared__ unsigned smem[4 * 768];    // 12 KB: bins (4x512) / csr (4x768)
  __shared__ float hld[16][68];         // 4.4 KB: fused gemm tile
  const int bid = blockIdx.x;
  const int t   = threadIdx.x;
  const int sb  = t >> 8, st = t & 255;

  // ---- phase 0: zero bucket_fill ----
  if (bid == 0 && t < 256) p.bfill[t] = 0;
  grid.sync();

  // ---- phase 1: blocks 0-48 bin edges (196 chunks); blocks 49-64 pack W ----
  if (bid < 49) {
    int v = bid * 4 + sb;               // 0..195, all active
    unsigned* lh   = smem + sb * 512;
    unsigned* lcur = lh + 256;
    lh[st] = 0;
    __syncthreads();
    int base = v * EB_CHUNK;
    int endv = min(base + EB_CHUNK, N_EDGES);
    for (int e = base + st; e < endv; e += 256)
      atomicAdd(&lh[((unsigned)p.e_dst[e]) >> 8], 1u);
    __syncthreads();
    unsigned c = lh[st];
    lcur[st] = st * ESTRIDE + (c ? atomicAdd(&p.bfill[st], c) : 0u);
    __syncthreads();
    for (int e = base + st; e < endv; e += 256) {
      unsigned d = (unsigned)p.e_dst[e];
      unsigned pos = atomicAdd(&lcur[d >> 8], 1u);
      p.temp[pos] = (unsigned)p.e_src[e] | ((d & 255u) << 16);
    }
  } else if (bid < 65) {
    int b = (bid - 49) * 4 + sb;        // 0..63
    if (b < 32)      pack_w<D_IN >(p.W1, p.Wh1, p.Wl1, b * 256 + st);
    else if (b < 48) pack_w<D_HID>(p.W2, p.Wh2, p.Wl2, (b - 32) * 256 + st);
    else             pack_w<D_HID>(p.W3, p.Wh3, p.Wl3, (b - 48) * 256 + st);
  }
  grid.sync();

  // ---- phase 2: blocks 0-48 CSR finalize (196 buckets); blocks 49+ layer-1 gemm ----
  if (bid < 49) {
    int b = bid * 4 + sb;               // bucket 0..195
    unsigned* hist  = smem + sb * 768;
    unsigned* sscan = hist + 256;
    unsigned* lfill = sscan + 256;
    unsigned ebase = b * ESTRIDE, ecnt = p.bfill[b], cbase = b * CSTRIDE;
    int nodes = min(256, N_NODES - b * 256);
    hist[st] = 0;
    __syncthreads();
    for (unsigned i = st; i < ecnt; i += 256)
      atomicAdd(&hist[(p.temp[ebase + i] >> 16) & 255u], 1u);
    __syncthreads();
    unsigned deg = (st < nodes) ? hist[st] + 1u : 0u;   // + self-loop
    sscan[st] = deg;
    __syncthreads();
    for (int off = 1; off < 256; off <<= 1) {
      unsigned v2 = (st >= off) ? sscan[st - off] : 0u;
      __syncthreads();
      sscan[st] += v2;
      __syncthreads();
    }
    unsigned excl = sscan[st] - deg;
    if (st < nodes) {
      int node = b * 256 + st;
      p.rowptr[node] = cbase + excl;
      p.rowend[node] = cbase + excl + deg;
      p.dis[node] = rsqrtf((float)deg);
      p.csr[cbase + excl] = (unsigned short)node;       // self-loop entry
    }
    lfill[st] = excl + 1u;
    __syncthreads();
    for (unsigned i = st; i < ecnt; i += 256) {
      unsigned v2 = p.temp[ebase + i];
      unsigned d = (v2 >> 16) & 255u;
      unsigned pos = atomicAdd(&lfill[d], 1u);
      p.csr[cbase + pos] = (unsigned short)(v2 & 0xFFFFu);
    }
  } else {
    int v = (bid - 49) * 4 + sb;        // 0..827, need < 782
    if (v < 782) gemm1_sub(v, st, p.x, p.Wh1, p.Wl1, p.xwA);
  }
  grid.sync();

  // ---- phase 3: layer-1 aggregate + layer-2 transform (fused), grid-strided ----
  for (int v = bid; v < 3125; v += 256)
    agg_gemm_tile(v, t, hld, (const float4*)p.xwA, p.rowptr, p.rowend, p.csr, p.dis,
                  p.b1, p.Wh2, p.Wl2, p.xwB);
  grid.sync();

  // ---- phase 4: layer-2 aggregate + layer-3 transform (fused) ----
  for (int v = bid; v < 3125; v += 256)
    agg_gemm_tile(v, t, hld, (const float4*)p.xwB, p.rowptr, p.rowend, p.csr, p.dis,
                  p.b2, p.Wh3, p.Wl3, p.xwA);
  grid.sync();

  // ---- phase 5: layer-3 aggregate -> fp32 out ----
  for (int v = bid; v < 3125; v += 256) {
    const int wave = t >> 6, lane = t & 63;
    const int sub = lane & 7, grp = lane >> 3;
    const int node = v * 16 + wave;
    float acc[8];
    agg_core(node, lane, sub, grp, (const float4*)p.xwA, p.rowptr, p.rowend, p.csr, p.dis, acc);
    if (grp == 0) {
      float4 ba = p.b3[sub * 2], bb = p.b3[sub * 2 + 1];
      float4 o0 = {acc[0] + ba.x, acc[1] + ba.y, acc[2] + ba.z, acc[3] + ba.w};
      float4 o1 = {acc[4] + bb.x, acc[5] + bb.y, acc[6] + bb.z, acc[7] + bb.w};
      p.out[(size_t)node * 16 + sub * 2]     = o0;
      p.out[(size_t)node * 16 + sub * 2 + 1] = o1;
    }
  }
}

// ---------------- launch ----------------

extern "C" void kernel_launch(void* const* d_in, const int* in_sizes, int n_in,
                              void* d_out, int out_size, void* d_ws, size_t ws_size,
                              hipStream_t stream) {
  const float* x    = (const float*)d_in[0];
  const int*   eidx = (const int*)d_in[1];      // [2][800000], int32
  const float* W1   = (const float*)d_in[2];
  const float* b1   = (const float*)d_in[3];
  const float* W2   = (const float*)d_in[4];
  const float* b2   = (const float*)d_in[5];
  const float* W3   = (const float*)d_in[6];
  const float* b3   = (const float*)d_in[7];

  size_t off = 0;
  auto alloc = [&](size_t bytes) -> void* {
    void* p = (char*)d_ws + off;
    off += (bytes + 255) & ~(size_t)255;
    return p;
  };
  unsigned*       rowptr = (unsigned*)alloc((size_t)N_NODES * 4);
  unsigned*       rowend = (unsigned*)alloc((size_t)N_NODES * 4);
  float*          dis    = (float*)alloc((size_t)N_NODES * 4);
  unsigned short* csr    = (unsigned short*)alloc((size_t)NB * CSTRIDE * 2);
  unsigned*       temp   = (unsigned*)alloc((size_t)NB * ESTRIDE * 4);
  unsigned*       bfill  = (unsigned*)alloc(256 * 4);
  __half*         xwA    = (__half*)alloc((size_t)N_PAD * 64 * 2);
  __half*         xwB    = (__half*)alloc((size_t)N_PAD * 64 * 2);
  __bf16*         Wh1    = (__bf16*)alloc((size_t)D_IN * 64 * 2);
  __bf16*         Wl1    = (__bf16*)alloc((size_t)D_IN * 64 * 2);
  __bf16*         Wh2    = (__bf16*)alloc((size_t)D_HID * 64 * 2);
  __bf16*         Wl2    = (__bf16*)alloc((size_t)D_HID * 64 * 2);
  __bf16*         Wh3    = (__bf16*)alloc((size_t)D_HID * 64 * 2);
  __bf16*         Wl3    = (__bf16*)alloc((size_t)D_HID * 64 * 2);

  MegaParams mp;
  mp.e_src = eidx; mp.e_dst = eidx + N_EDGES;
  mp.bfill = bfill; mp.temp = temp;
  mp.W1 = W1; mp.W2 = W2; mp.W3 = W3;
  mp.Wh1 = Wh1; mp.Wl1 = Wl1; mp.Wh2 = Wh2; mp.Wl2 = Wl2; mp.Wh3 = Wh3; mp.Wl3 = Wl3;
  mp.rowptr = rowptr; mp.rowend = rowend; mp.dis = dis; mp.csr = csr;
  mp.x = x; mp.xwA = xwA; mp.xwB = xwB;
  mp.b1 = (const float4*)b1; mp.b2 = (const float4*)b2; mp.b3 = (const float4*)b3;
  mp.out = (float4*)d_out;

  void* args[] = { &mp };
  hipLaunchCooperativeKernel((const void*)k_mega, dim3(256), dim3(1024), args, 0, stream);
}

// Round 14
// 125.116 us; speedup vs baseline: 2.4554x; 2.4554x over previous
//
#include <hip/hip_runtime.h>
#include <hip/hip_fp16.h>

#define N_NODES 50000
#define N_PAD   50048                 // padded rows for 64-row GEMM blocks
#define N_EDGES 800000
#define D_IN    128
#define D_HID   64

#define NB         196                // buckets of 256 nodes
#define EB_CHUNK   4096               // edges per binning block
#define BIN_BLOCKS 196                // ceil(N_EDGES / EB_CHUNK)
#define ESTRIDE    4864               // per-bucket temp capacity (mean 4096 + 12 sigma)
#define CSTRIDE    (ESTRIDE + 256)    // per-bucket csr capacity (+256 self-loops)

typedef __bf16 bf16x8 __attribute__((ext_vector_type(8)));
typedef float  f32x4  __attribute__((ext_vector_type(4)));

// ---------------- W -> MFMA-B-fragment-order bf16 hi/lo ----------------

template <int K>
__device__ __forceinline__ void pack_w(const float* __restrict__ W,
                                       __bf16* __restrict__ Bh, __bf16* __restrict__ Bl, int i) {
  constexpr int KS = K / 32;
  int j = i & 7, lane = (i >> 3) & 63, rest = i >> 9;
  int ct = rest / KS, ks = rest - ct * KS;
  int k = ks * 32 + ((lane >> 4) << 3) + j;
  int c = ct * 16 + (lane & 15);
  float v = W[k * 64 + c];
  __bf16 hb = (__bf16)v;
  Bh[i] = hb;
  Bl[i] = (__bf16)(v - (float)hb);
}

// ---------------- binning (+ fused W split): LDS hist -> global reserve -> scatter ----------------

__global__ __launch_bounds__(256) void k_bins_sw(const int* __restrict__ src,
                                                 const int* __restrict__ dst,
                                                 unsigned* __restrict__ bucket_fill,
                                                 unsigned* __restrict__ temp,
                                                 const float* __restrict__ W1,
                                                 const float* __restrict__ W2,
                                                 const float* __restrict__ W3,
                                                 __bf16* __restrict__ Wh1, __bf16* __restrict__ Wl1,
                                                 __bf16* __restrict__ Wh2, __bf16* __restrict__ Wl2,
                                                 __bf16* __restrict__ Wh3, __bf16* __restrict__ Wl3) {
  __shared__ unsigned lh[256], lcur[256];
  int blk = blockIdx.x, t = threadIdx.x;
  if (blk >= BIN_BLOCKS) {                       // W-split role
    int b = blk - BIN_BLOCKS;
    if (b < 32)      pack_w<D_IN >(W1, Wh1, Wl1, b * 256 + t);
    else if (b < 48) pack_w<D_HID>(W2, Wh2, Wl2, (b - 32) * 256 + t);
    else             pack_w<D_HID>(W3, Wh3, Wl3, (b - 48) * 256 + t);
    return;
  }
  lh[t] = 0;
  __syncthreads();
  int base = blk * EB_CHUNK;
  int endv = min(base + EB_CHUNK, N_EDGES);
  for (int e = base + t; e < endv; e += 256)
    atomicAdd(&lh[((unsigned)dst[e]) >> 8], 1u);
  __syncthreads();
  unsigned c = lh[t];
  lcur[t] = t * ESTRIDE + (c ? atomicAdd(&bucket_fill[t], c) : 0u);
  __syncthreads();
  for (int e = base + t; e < endv; e += 256) {
    unsigned d = (unsigned)dst[e];
    unsigned pos = atomicAdd(&lcur[d >> 8], 1u);
    temp[pos] = (unsigned)src[e] | ((d & 255u) << 16);   // src < 2^16, dstlocal 8b
  }
}

// ---------------- dense transform body (MFMA, split-bf16 3 products) ----------------

template <int K, bool FIRST>
__device__ __forceinline__ void gemm_body(int bid,
                                          const float* __restrict__ Xf,
                                          const __bf16* __restrict__ Bh,
                                          const __bf16* __restrict__ Bl,
                                          __half* __restrict__ Y) {
  constexpr int KS = K / 32;
  const int tid  = threadIdx.x;
  const int wave = tid >> 6;
  const int lane = tid & 63;
  const int row0 = bid * 64 + wave * 16;
  const int row_a = min(row0 + (lane & 15), N_NODES - 1);
  const int q8 = (lane >> 4) << 3;

  f32x4 acc[4];
#pragma unroll
  for (int ct = 0; ct < 4; ct++) acc[ct] = (f32x4){0.f, 0.f, 0.f, 0.f};

#pragma unroll
  for (int ks = 0; ks < KS; ks++) {
    bf16x8 ah, al;
    const float4* xr4 = reinterpret_cast<const float4*>(Xf + (size_t)row_a * K);
    float4 f0 = xr4[ks * 8 + (q8 >> 2) + 0];
    float4 f1 = xr4[ks * 8 + (q8 >> 2) + 1];
#pragma unroll
    for (int j = 0; j < 4; j++) {
      float a0 = (&f0.x)[j], a1 = (&f1.x)[j];
      __bf16 h0 = (__bf16)a0, h1 = (__bf16)a1;
      ah[j] = h0;     al[j] = (__bf16)(a0 - (float)h0);
      ah[4 + j] = h1; al[4 + j] = (__bf16)(a1 - (float)h1);
    }
#pragma unroll
    for (int ct = 0; ct < 4; ct++) {
      bf16x8 bh = *reinterpret_cast<const bf16x8*>(Bh + (size_t)((ct * KS + ks) * 64 + lane) * 8);
      bf16x8 bl = *reinterpret_cast<const bf16x8*>(Bl + (size_t)((ct * KS + ks) * 64 + lane) * 8);
      acc[ct] = __builtin_amdgcn_mfma_f32_16x16x32_bf16(ah, bh, acc[ct], 0, 0, 0);
      acc[ct] = __builtin_amdgcn_mfma_f32_16x16x32_bf16(ah, bl, acc[ct], 0, 0, 0);
      acc[ct] = __builtin_amdgcn_mfma_f32_16x16x32_bf16(al, bh, acc[ct], 0, 0, 0);
    }
  }

  // C/D: col = lane&15, row = (lane>>4)*4 + reg   [m89-verified]
  const int rbase = row0 + ((lane >> 4) << 2);
  const int c     = lane & 15;
#pragma unroll
  for (int ct = 0; ct < 4; ct++)
#pragma unroll
    for (int r = 0; r < 4; r++) {
      int row = rbase + r;
      if (row < N_NODES)
        Y[(size_t)row * 64 + ct * 16 + c] = __float2half_rn(acc[ct][r]);
    }
}

// ---------------- per-bucket CSR finalize (+ fused layer-1 gemm) ----------------

__global__ __launch_bounds__(256) void k_csr_gemm1(const unsigned* __restrict__ temp,
                                                   const unsigned* __restrict__ bucket_fill,
                                                   unsigned* __restrict__ rowptr,
                                                   unsigned* __restrict__ rowend,
                                                   float* __restrict__ dis,
                                                   unsigned short* __restrict__ csr,
                                                   const float* __restrict__ x,
                                                   const __bf16* __restrict__ Wh1,
                                                   const __bf16* __restrict__ Wl1,
                                                   __half* __restrict__ xw) {
  __shared__ unsigned hist[256], sscan[256], lfill[256];
  if (blockIdx.x >= NB) {                 // gemm role (independent of CSR)
    gemm_body<D_IN, true>(blockIdx.x - NB, x, Wh1, Wl1, xw);
    return;
  }
  int b = blockIdx.x, t = threadIdx.x;
  unsigned ebase = b * ESTRIDE, ecnt = bucket_fill[b], cbase = b * CSTRIDE;
  int nodes = min(256, N_NODES - b * 256);
  hist[t] = 0;
  __syncthreads();
  for (unsigned i = t; i < ecnt; i += 256)
    atomicAdd(&hist[(temp[ebase + i] >> 16) & 255u], 1u);
  __syncthreads();
  unsigned deg = (t < nodes) ? hist[t] + 1u : 0u;        // + self-loop
  sscan[t] = deg;
  __syncthreads();
  for (int off = 1; off < 256; off <<= 1) {
    unsigned v = (t >= off) ? sscan[t - off] : 0u;
    __syncthreads();
    sscan[t] += v;
    __syncthreads();
  }
  unsigned excl = sscan[t] - deg;
  if (t < nodes) {
    int node = b * 256 + t;
    rowptr[node] = cbase + excl;
    rowend[node] = cbase + excl + deg;
    dis[node] = rsqrtf((float)deg);
    csr[cbase + excl] = (unsigned short)node;            // self-loop entry
  }
  lfill[t] = excl + 1u;
  __syncthreads();
  for (unsigned i = t; i < ecnt; i += 256) {
    unsigned v = temp[ebase + i];
    unsigned d = (v >> 16) & 255u;
    unsigned pos = atomicAdd(&lfill[d], 1u);
    csr[cbase + pos] = (unsigned short)(v & 0xFFFFu);
  }
}

// ---------------- agg core (R9 proven structure), result in acc[8] on grp==0 lanes ----------------

__device__ __forceinline__ void agg_core(int node, int lane, int sub, int grp,
                                         const float4* __restrict__ XW4,
                                         const unsigned* __restrict__ rowptr,
                                         const unsigned* __restrict__ rowend,
                                         const unsigned short* __restrict__ csr,
                                         const float* __restrict__ dis,
                                         float* __restrict__ accout) {
  const float disd = dis[node];
  unsigned beg = rowptr[node], end = rowend[node];
  float acc0[8] = {0,0,0,0,0,0,0,0};
  float acc1[8] = {0,0,0,0,0,0,0,0};

  for (unsigned j = beg; j < end; j += 64) {
    int nj = (int)min(64u, end - j);
    unsigned s = 0u; float nrm = 0.f;
    if (lane < nj) {
      s = csr[j + lane];                    // 2B coalesced
      nrm = dis[s] * disd;
    }
    for (int k = 0; k < nj; k += 16) {
      int e0 = k + grp;
      unsigned s0 = (unsigned)__shfl((int)s, e0);
      float    n0 = __shfl(nrm, e0);
      float4 v0 = XW4[(size_t)s0 * 8 + sub];           // 16B = 8 fp16
      const __half2* h0 = reinterpret_cast<const __half2*>(&v0);
#pragma unroll
      for (int q = 0; q < 4; q++) {
        float2 f = __half22float2(h0[q]);
        acc0[2*q]   += n0 * f.x;
        acc0[2*q+1] += n0 * f.y;
      }
      if (k + 8 < nj) {                                 // wave-uniform guard
        int e1 = k + grp + 8;
        unsigned s1 = (unsigned)__shfl((int)s, e1);
        float    n1 = __shfl(nrm, e1);
        float4 v1 = XW4[(size_t)s1 * 8 + sub];
        const __half2* h1 = reinterpret_cast<const __half2*>(&v1);
#pragma unroll
        for (int q = 0; q < 4; q++) {
          float2 f = __half22float2(h1[q]);
          acc1[2*q]   += n1 * f.x;
          acc1[2*q+1] += n1 * f.y;
        }
      }
    }
  }

#pragma unroll
  for (int i = 0; i < 8; i++) {
    float a = acc0[i] + acc1[i];
    a += __shfl_xor(a, 8);
    a += __shfl_xor(a, 16);
    a += __shfl_xor(a, 32);
    accout[i] = a;
  }
}

// ---------------- fused: aggregate(+bias,relu) -> LDS -> next-layer gemm ----------------
// 1024 threads = 16 waves, wave-per-node (16 nodes/block = one 16-row gemm tile).

__global__ __launch_bounds__(1024) void k_agg_gemm(const float4* __restrict__ XW4,
                                                   const unsigned* __restrict__ rowptr,
                                                   const unsigned* __restrict__ rowend,
                                                   const unsigned short* __restrict__ csr,
                                                   const float* __restrict__ dis,
                                                   const float4* __restrict__ bias4,
                                                   const __bf16* __restrict__ Bh,
                                                   const __bf16* __restrict__ Bl,
                                                   __half* __restrict__ Y) {
  __shared__ float hld[16][68];                  // fp32 h tile, +4 pad
  const int wave = threadIdx.x >> 6;             // node within block
  const int lane = threadIdx.x & 63;
  const int sub  = lane & 7;
  const int grp  = lane >> 3;
  const int node = blockIdx.x * 16 + wave;       // 3125*16 = 50000 exact

  float acc[8];
  agg_core(node, lane, sub, grp, XW4, rowptr, rowend, csr, dis, acc);

  if (grp == 0) {
    float4 ba = bias4[sub * 2], bb = bias4[sub * 2 + 1];
    acc[0] += ba.x; acc[1] += ba.y; acc[2] += ba.z; acc[3] += ba.w;
    acc[4] += bb.x; acc[5] += bb.y; acc[6] += bb.z; acc[7] += bb.w;
    float4 o0, o1;
    o0.x = fmaxf(acc[0], 0.f); o0.y = fmaxf(acc[1], 0.f);
    o0.z = fmaxf(acc[2], 0.f); o0.w = fmaxf(acc[3], 0.f);
    o1.x = fmaxf(acc[4], 0.f); o1.y = fmaxf(acc[5], 0.f);
    o1.z = fmaxf(acc[6], 0.f); o1.w = fmaxf(acc[7], 0.f);
    *reinterpret_cast<float4*>(&hld[wave][sub * 8])     = o0;
    *reinterpret_cast<float4*>(&hld[wave][sub * 8 + 4]) = o1;
  }
  __syncthreads();

  // gemm phase: waves 0..3, wave = col-tile ct. A from LDS fp32 (split in-register).
  if (wave < 4) {
    const int ct = wave;
    const int r16 = lane & 15;
    const int q8  = (lane >> 4) << 3;
    f32x4 gacc = (f32x4){0.f, 0.f, 0.f, 0.f};
#pragma unroll
    for (int ks = 0; ks < 2; ks++) {
      float4 f0 = *reinterpret_cast<const float4*>(&hld[r16][ks * 32 + q8]);
      float4 f1 = *reinterpret_cast<const float4*>(&hld[r16][ks * 32 + q8 + 4]);
      bf16x8 ah, al;
#pragma unroll
      for (int j = 0; j < 4; j++) {
        float a0 = (&f0.x)[j], a1 = (&f1.x)[j];
        __bf16 h0 = (__bf16)a0, h1 = (__bf16)a1;
        ah[j] = h0;     al[j] = (__bf16)(a0 - (float)h0);
        ah[4 + j] = h1; al[4 + j] = (__bf16)(a1 - (float)h1);
      }
      bf16x8 bh = *reinterpret_cast<const bf16x8*>(Bh + (size_t)((ct * 2 + ks) * 64 + lane) * 8);
      bf16x8 bl = *reinterpret_cast<const bf16x8*>(Bl + (size_t)((ct * 2 + ks) * 64 + lane) * 8);
      gacc = __builtin_amdgcn_mfma_f32_16x16x32_bf16(ah, bh, gacc, 0, 0, 0);
      gacc = __builtin_amdgcn_mfma_f32_16x16x32_bf16(ah, bl, gacc, 0, 0, 0);
      gacc = __builtin_amdgcn_mfma_f32_16x16x32_bf16(al, bh, gacc, 0, 0, 0);
    }
    const int rbase = blockIdx.x * 16 + ((lane >> 4) << 2);
    const int c     = lane & 15;
#pragma unroll
    for (int r = 0; r < 4; r++)
      Y[(size_t)(rbase + r) * 64 + ct * 16 + c] = __float2half_rn(gacc[r]);
  }
}

// ---------------- final aggregate (layer 3): fp32 out, no relu ----------------

__global__ __launch_bounds__(256) void k_agg3(const float4* __restrict__ XW4,
                                              const unsigned* __restrict__ rowptr,
                                              const unsigned* __restrict__ rowend,
                                              const unsigned short* __restrict__ csr,
                                              const float* __restrict__ dis,
                                              const float4* __restrict__ bias4,
                                              float4* __restrict__ OUT4) {
  int node = (int)((blockIdx.x * blockDim.x + threadIdx.x) >> 6);
  int lane = threadIdx.x & 63;
  if (node >= N_NODES) return;
  const int sub = lane & 7;
  const int grp = lane >> 3;

  float acc[8];
  agg_core(node, lane, sub, grp, XW4, rowptr, rowend, csr, dis, acc);

  if (grp == 0) {
    float4 ba = bias4[sub * 2], bb = bias4[sub * 2 + 1];
    float4 o0 = {acc[0] + ba.x, acc[1] + ba.y, acc[2] + ba.z, acc[3] + ba.w};
    float4 o1 = {acc[4] + bb.x, acc[5] + bb.y, acc[6] + bb.z, acc[7] + bb.w};
    OUT4[(size_t)node * 16 + sub * 2]     = o0;
    OUT4[(size_t)node * 16 + sub * 2 + 1] = o1;
  }
}

// ---------------- launch ----------------

extern "C" void kernel_launch(void* const* d_in, const int* in_sizes, int n_in,
                              void* d_out, int out_size, void* d_ws, size_t ws_size,
                              hipStream_t stream) {
  const float* x    = (const float*)d_in[0];
  const int*   eidx = (const int*)d_in[1];      // [2][800000], int32
  const float* W1   = (const float*)d_in[2];
  const float* b1   = (const float*)d_in[3];
  const float* W2   = (const float*)d_in[4];
  const float* b2   = (const float*)d_in[5];
  const float* W3   = (const float*)d_in[6];
  const float* b3   = (const float*)d_in[7];
  float* out = (float*)d_out;

  const int* e_src = eidx;
  const int* e_dst = eidx + N_EDGES;

  size_t off = 0;
  auto alloc = [&](size_t bytes) -> void* {
    void* p = (char*)d_ws + off;
    off += (bytes + 255) & ~(size_t)255;
    return p;
  };
  unsigned*       rowptr = (unsigned*)alloc((size_t)N_NODES * 4);
  unsigned*       rowend = (unsigned*)alloc((size_t)N_NODES * 4);
  float*          dis    = (float*)alloc((size_t)N_NODES * 4);
  unsigned short* csr    = (unsigned short*)alloc((size_t)NB * CSTRIDE * 2);
  unsigned*       temp   = (unsigned*)alloc((size_t)NB * ESTRIDE * 4);
  unsigned*       bfill  = (unsigned*)alloc(256 * 4);
  __half*         xwA    = (__half*)alloc((size_t)N_PAD * 64 * 2);
  __half*         xwB    = (__half*)alloc((size_t)N_PAD * 64 * 2);
  __bf16*         Wh1    = (__bf16*)alloc((size_t)D_IN * 64 * 2);
  __bf16*         Wl1    = (__bf16*)alloc((size_t)D_IN * 64 * 2);
  __bf16*         Wh2    = (__bf16*)alloc((size_t)D_HID * 64 * 2);
  __bf16*         Wl2    = (__bf16*)alloc((size_t)D_HID * 64 * 2);
  __bf16*         Wh3    = (__bf16*)alloc((size_t)D_HID * 64 * 2);
  __bf16*         Wl3    = (__bf16*)alloc((size_t)D_HID * 64 * 2);

  const int gemm_grid  = N_PAD / 64;                  // 782
  const int fused_grid = N_NODES / 16;                // 3125
  const int agg_grid   = (N_NODES * 64 + 255) / 256;  // 12500

  // ---- graph build + W split + layer-1 gemm ----
  hipMemsetAsync(bfill, 0, 256 * 4, stream);
  k_bins_sw<<<BIN_BLOCKS + 64, 256, 0, stream>>>(e_src, e_dst, bfill, temp,
                                                 W1, W2, W3, Wh1, Wl1, Wh2, Wl2, Wh3, Wl3);
  k_csr_gemm1<<<NB + gemm_grid, 256, 0, stream>>>(temp, bfill, rowptr, rowend,
                                                  dis, csr, x, Wh1, Wl1, xwA);
  // ---- layer 1 aggregate + layer 2 transform (fused) ----
  k_agg_gemm<<<fused_grid, 1024, 0, stream>>>((const float4*)xwA, rowptr, rowend, csr, dis,
                                              (const float4*)b1, Wh2, Wl2, xwB);
  // ---- layer 2 aggregate + layer 3 transform (fused) ----
  k_agg_gemm<<<fused_grid, 1024, 0, stream>>>((const float4*)xwB, rowptr, rowend, csr, dis,
                                              (const float4*)b2, Wh3, Wl3, xwA);
  // ---- layer 3 aggregate ----
  k_agg3<<<agg_grid, 256, 0, stream>>>((const float4*)xwA, rowptr, rowend, csr, dis,
                                       (const float4*)b3, (float4*)out);
}